// Round 1
// baseline (502.502 us; speedup 1.0000x reference)
//
#include <hip/hip_runtime.h>

// Problem constants (from reference setup_inputs)
constexpr int BB    = 16;
constexpr int TT    = 12;
constexpr int NN    = 307;
constexpr int DD    = 64;
constexpr int TN    = TT * NN;        // 3684
constexpr int ROWSX = BB * TT * NN;   // 58944
constexpr int ROWSH = BB * NN;        // 4912
constexpr int KC    = 8;              // K-split for o-GEMM
constexpr int KCH   = 461;            // ceil(3684/8)
constexpr float SCALE   = 0.125f;     // 1/sqrt(64)
constexpr float NEGINF  = -1e30f;

__device__ __forceinline__ float wred_sum(float v) {
#pragma unroll
    for (int m = 32; m > 0; m >>= 1) v += __shfl_xor(v, m, 64);
    return v;
}
__device__ __forceinline__ float wred_max(float v) {
#pragma unroll
    for (int m = 32; m > 0; m >>= 1) v = fmaxf(v, __shfl_xor(v, m, 64));
    return v;
}

// ---------------------------------------------------------------------------
// Fold q/k projections: dg = q.k = qt.x_ + c
//   M[e][d] = sum_{d'} q_w[d'][e] * k_w[d'][d]
//   b2[d]   = sum_{d'} q_b[d'] * k_w[d'][d]
//   v[e]    = sum_{d'} q_w[d'][e] * k_b[d']
//   cc      = q_b . k_b
// ---------------------------------------------------------------------------
__global__ void fold_k(const float* __restrict__ qw, const float* __restrict__ qb,
                       const float* __restrict__ kw, const float* __restrict__ kb,
                       float* __restrict__ M, float* __restrict__ b2,
                       float* __restrict__ vv, float* __restrict__ cc) {
    int e = blockIdx.x, d = threadIdx.x;
    float acc = 0.f;
    for (int dp = 0; dp < 64; ++dp) acc += qw[dp * 64 + e] * kw[dp * 64 + d];
    M[e * 64 + d] = acc;
    float vp = wred_sum(qw[d * 64 + e] * kb[d]);
    if (d == 0) vv[e] = vp;
    if (e == 0) {
        float b = 0.f;
        for (int dp = 0; dp < 64; ++dp) b += qb[dp] * kw[dp * 64 + d];
        b2[d] = b;
        float cp = wred_sum(qb[d] * kb[d]);
        if (d == 0) *cc = cp;
    }
}

// ---------------------------------------------------------------------------
// LayerNorm of x -> xn   (one wave per 64-elem row)
// ---------------------------------------------------------------------------
__global__ __launch_bounds__(256) void ln_k(const float* __restrict__ x,
                                            const float* __restrict__ g,
                                            const float* __restrict__ b,
                                            float* __restrict__ xn, int nrows) {
    int w = threadIdx.x >> 6, l = threadIdx.x & 63;
    int r = blockIdx.x * 4 + w;
    if (r >= nrows) return;
    float val = x[r * 64 + l];
    float mu  = wred_sum(val) * (1.f / 64.f);
    float dv  = val - mu;
    float var = wred_sum(dv * dv) * (1.f / 64.f);
    xn[r * 64 + l] = dv * rsqrtf(var + 1e-5f) * g[l] + b[l];
}

// ---------------------------------------------------------------------------
// qt[row] = y_ @ M + b2 ;  cq[row] = y_.v + cc     (one wave per row)
// ---------------------------------------------------------------------------
__global__ __launch_bounds__(256) void qt_k(const float* __restrict__ xn,
                                            const float* __restrict__ M,
                                            const float* __restrict__ b2,
                                            const float* __restrict__ vv,
                                            const float* __restrict__ ccp,
                                            float* __restrict__ qt,
                                            float* __restrict__ cq) {
    int w = threadIdx.x >> 6, l = threadIdx.x & 63;
    int rr = blockIdx.x * 4 + w;
    if (rr >= ROWSH) return;
    int b = rr / NN, n = rr % NN;
    float y = xn[((b * TT + (TT - 1)) * NN + n) * 64 + l];
    float acc = b2[l];
#pragma unroll
    for (int e = 0; e < 64; ++e) {
        float ye = __shfl(y, e, 64);
        acc += ye * M[e * 64 + l];
    }
    qt[rr * 64 + l] = acc;
    float cpart = wred_sum(y * vv[l]);
    if (l == 0) cq[rr] = cpart + *ccp;
}

// ---------------------------------------------------------------------------
// Score: sag[b,n,j] = sigmoid((qt[b,n].xn[b,j] + c)*scale) * stg * scale
// tile 64 n-rows x 128 j-cols, micro 8x4, cyclic lane distribution
// ---------------------------------------------------------------------------
__global__ __launch_bounds__(256) void score_k(const float* __restrict__ qt,
                                               const float* __restrict__ cq,
                                               const float* __restrict__ xn,
                                               const float* __restrict__ stg,
                                               float* __restrict__ sag) {
    __shared__ float sA[64 * 65];
    __shared__ float sB[128 * 65];
    int bb = blockIdx.z;
    int n0 = blockIdx.y * 64;
    int j0 = blockIdx.x * 128;
    int t  = threadIdx.x;
#pragma unroll
    for (int i = 0; i < 16; ++i) {
        int f = t + 256 * i, row = f >> 6, col = f & 63;
        int n = n0 + row;
        sA[row * 65 + col] = (n < NN) ? qt[(bb * NN + n) * 64 + col] : 0.f;
    }
#pragma unroll
    for (int i = 0; i < 32; ++i) {
        int f = t + 256 * i, row = f >> 6, col = f & 63;
        int j = j0 + row;
        sB[row * 65 + col] = (j < TN) ? xn[(bb * TN + j) * 64 + col] : 0.f;
    }
    __syncthreads();
    int tr = t >> 5, tc = t & 31;
    float acc[8][4];
#pragma unroll
    for (int a = 0; a < 8; ++a)
#pragma unroll
        for (int c = 0; c < 4; ++c) acc[a][c] = 0.f;
#pragma unroll 4
    for (int d = 0; d < 64; ++d) {
        float av[8], bv[4];
#pragma unroll
        for (int ri = 0; ri < 8; ++ri) av[ri] = sA[(tr + 8 * ri) * 65 + d];
#pragma unroll
        for (int ci = 0; ci < 4; ++ci) bv[ci] = sB[(tc + 32 * ci) * 65 + d];
#pragma unroll
        for (int ri = 0; ri < 8; ++ri)
#pragma unroll
            for (int ci = 0; ci < 4; ++ci) acc[ri][ci] += av[ri] * bv[ci];
    }
#pragma unroll
    for (int ri = 0; ri < 8; ++ri) {
        int n = n0 + tr + 8 * ri;
        if (n >= NN) continue;
        float cn = cq[bb * NN + n];
#pragma unroll
        for (int ci = 0; ci < 4; ++ci) {
            int j = j0 + tc + 32 * ci;
            if (j >= TN) continue;
            float dg = (acc[ri][ci] + cn) * SCALE;
            float s  = 1.f / (1.f + __expf(-dg));
            int idx  = (bb * NN + n) * TN + j;
            sag[idx] = s * stg[idx] * SCALE;
        }
    }
}

// ---------------------------------------------------------------------------
// Top-k (exact radix select on float bits, values >= 0) + softmax, in place.
// One block per (b,n) row, values register-resident (15/thread).
// ---------------------------------------------------------------------------
__global__ __launch_bounds__(256) void topk_k(float* __restrict__ sag,
                                              const int* __restrict__ topk_p) {
    __shared__ float red[4];
    __shared__ int   hist[256];
    __shared__ int   bc_bin, bc_rk;
    int row = blockIdx.x;
    int t   = threadIdx.x;
    int base = row * TN;
    float vals[15];
#pragma unroll
    for (int s = 0; s < 15; ++s) {
        int j = t + 256 * s;
        vals[s] = (j < TN) ? sag[base + j] : NEGINF;
    }
    float vm = NEGINF;
#pragma unroll
    for (int s = 0; s < 15; ++s) vm = fmaxf(vm, vals[s]);
    vm = wred_max(vm);
    int wid = t >> 6;
    if ((t & 63) == 0) red[wid] = vm;
    __syncthreads();
    vm = fmaxf(fmaxf(red[0], red[1]), fmaxf(red[2], red[3]));
    __syncthreads();

    int topk = *topk_p;
    float thr = -3.0e38f;  // select-all sentinel
    if (topk > 0) {
        int kk = (topk < 5) ? topk * NN : topk;
        if (kk > TN) kk = TN;
        unsigned prefix = 0;
        int rk = kk;
        for (int pass = 0; pass < 4; ++pass) {
            int shift = 24 - 8 * pass;
            hist[t] = 0;
            __syncthreads();
#pragma unroll
            for (int s = 0; s < 15; ++s) {
                int j = t + 256 * s;
                if (j < TN) {
                    unsigned u = __float_as_uint(vals[s]);
                    bool m = (pass == 0) || ((u >> (shift + 8)) == (prefix >> (shift + 8)));
                    if (m) atomicAdd(&hist[(u >> shift) & 255], 1);
                }
            }
            __syncthreads();
            // inclusive suffix sum over 256 bins
            for (int off = 1; off < 256; off <<= 1) {
                int vsum = hist[t] + ((t + off < 256) ? hist[t + off] : 0);
                __syncthreads();
                hist[t] = vsum;
                __syncthreads();
            }
            int sfx  = hist[t];
            int sfx1 = (t == 255) ? 0 : hist[t + 1];
            if (sfx >= rk && sfx1 < rk) { bc_bin = t; bc_rk = rk - sfx1; }
            __syncthreads();
            prefix |= ((unsigned)bc_bin) << shift;
            rk = bc_rk;
            __syncthreads();
        }
        thr = __uint_as_float(prefix);  // exact kk-th largest
    }

    // softmax over strictly-greater-than-thr elements
    float local = 0.f;
#pragma unroll
    for (int s = 0; s < 15; ++s) {
        int j = t + 256 * s;
        float e = 0.f;
        if (j < TN && vals[s] > thr) e = __expf(vals[s] - vm);
        vals[s] = e;
        local += e;
    }
    local = wred_sum(local);
    if ((t & 63) == 0) red[wid] = local;
    __syncthreads();
    float S = red[0] + red[1] + red[2] + red[3];
    if (S > 0.f) {
        float inv = 1.f / S;
#pragma unroll
        for (int s = 0; s < 15; ++s) {
            int j = t + 256 * s;
            if (j < TN) sag[base + j] = vals[s] * inv;
        }
    } else {  // degenerate: reference softmax of all-NEG_INF -> uniform
        float u = 1.f / (float)TN;
#pragma unroll
        for (int s = 0; s < 15; ++s) {
            int j = t + 256 * s;
            if (j < TN) sag[base + j] = u;
        }
    }
}

// ---------------------------------------------------------------------------
// o-GEMM (K-split): opart[kc][b,n,:] = sum_{j in chunk} W[n,j] * xn[b,j,:]
// tile 64n x 64d, micro 4x4
// ---------------------------------------------------------------------------
__global__ __launch_bounds__(256) void ogemm_k(const float* __restrict__ sag,
                                               const float* __restrict__ xn,
                                               float* __restrict__ opart) {
    __shared__ float sW[64 * 65];
    __shared__ float sX[64 * 65];
    int bb = blockIdx.z;
    int n0 = blockIdx.y * 64;
    int kc = blockIdx.x;
    int t  = threadIdx.x;
    int kbeg = kc * KCH;
    int kend = min(TN, kbeg + KCH);
    int tr = t >> 4, tc = t & 15;
    float acc[4][4];
#pragma unroll
    for (int a = 0; a < 4; ++a)
#pragma unroll
        for (int c = 0; c < 4; ++c) acc[a][c] = 0.f;
    for (int k0 = kbeg; k0 < kend; k0 += 64) {
#pragma unroll
        for (int i = 0; i < 16; ++i) {
            int f = t + 256 * i, row = f >> 6, col = f & 63;
            int n = n0 + row, k = k0 + col;
            sW[row * 65 + col] = (n < NN && k < kend) ? sag[(bb * NN + n) * TN + k] : 0.f;
            int kr = k0 + row;
            sX[row * 65 + col] = (kr < kend) ? xn[(bb * TN + kr) * 64 + col] : 0.f;
        }
        __syncthreads();
#pragma unroll 4
        for (int kj = 0; kj < 64; ++kj) {
            float wv[4], xv[4];
#pragma unroll
            for (int ri = 0; ri < 4; ++ri) wv[ri] = sW[(tr + 16 * ri) * 65 + kj];
#pragma unroll
            for (int ci = 0; ci < 4; ++ci) xv[ci] = sX[kj * 65 + tc + 16 * ci];
#pragma unroll
            for (int ri = 0; ri < 4; ++ri)
#pragma unroll
                for (int ci = 0; ci < 4; ++ci) acc[ri][ci] += wv[ri] * xv[ci];
        }
        __syncthreads();
    }
#pragma unroll
    for (int ri = 0; ri < 4; ++ri) {
        int n = n0 + tr + 16 * ri;
        if (n >= NN) continue;
#pragma unroll
        for (int ci = 0; ci < 4; ++ci) {
            int c = tc + 16 * ci;
            opart[(kc * ROWSH + bb * NN + n) * 64 + c] = acc[ri][ci];
        }
    }
}

// ---------------------------------------------------------------------------
// h = sum_kc opart + y_
// ---------------------------------------------------------------------------
__global__ void hred_k(const float* __restrict__ opart, const float* __restrict__ xn,
                       float* __restrict__ h) {
    int idx = blockIdx.x * 256 + threadIdx.x;
    if (idx >= ROWSH * 64) return;
    int r = idx >> 6, d = idx & 63;
    int b = r / NN, n = r % NN;
    float acc = 0.f;
#pragma unroll
    for (int kc = 0; kc < KC; ++kc) acc += opart[kc * ROWSH * 64 + idx];
    acc += xn[((b * TT + (TT - 1)) * NN + n) * 64 + d];
    h[idx] = acc;
}

// ---------------------------------------------------------------------------
// FFN: out = h + (relu(LN(h)@fc1^T + b1)@fc2^T + b2)    16 rows/block
// ---------------------------------------------------------------------------
__global__ __launch_bounds__(256) void ffn_k(const float* __restrict__ h,
                                             const float* __restrict__ g,
                                             const float* __restrict__ bln,
                                             const float* __restrict__ fc1w,
                                             const float* __restrict__ fc1b,
                                             const float* __restrict__ fc2w,
                                             const float* __restrict__ fc2b,
                                             float* __restrict__ out) {
    __shared__ float zbuf[16 * 65];
    __shared__ float wbuf[256 * 65];  // fc1 [256][64] s65; reused fc2 [64][257]
    __shared__ float abuf[16 * 257];
    int t = threadIdx.x;
    int r0 = blockIdx.x * 16;
    int w = t >> 6, l = t & 63;
    for (int q = 0; q < 4; ++q) {
        int rloc = w * 4 + q;
        float val = h[(r0 + rloc) * 64 + l];
        float mu  = wred_sum(val) * (1.f / 64.f);
        float dv  = val - mu;
        float var = wred_sum(dv * dv) * (1.f / 64.f);
        zbuf[rloc * 65 + l] = dv * rsqrtf(var + 1e-5f) * g[l] + bln[l];
    }
#pragma unroll
    for (int i = 0; i < 64; ++i) {
        int f = t + 256 * i, row = f >> 6, col = f & 63;
        wbuf[row * 65 + col] = fc1w[f];
    }
    __syncthreads();
    {  // GEMM1: 16 x 256 = z @ fc1^T, relu
        int tr = t >> 6, tc = t & 63;
        float acc[4][4];
#pragma unroll
        for (int a = 0; a < 4; ++a)
#pragma unroll
            for (int c = 0; c < 4; ++c) acc[a][c] = 0.f;
#pragma unroll 4
        for (int d = 0; d < 64; ++d) {
            float av[4], bv[4];
#pragma unroll
            for (int ri = 0; ri < 4; ++ri) av[ri] = zbuf[(tr + 4 * ri) * 65 + d];
#pragma unroll
            for (int ci = 0; ci < 4; ++ci) bv[ci] = wbuf[(tc + 64 * ci) * 65 + d];
#pragma unroll
            for (int ri = 0; ri < 4; ++ri)
#pragma unroll
                for (int ci = 0; ci < 4; ++ci) acc[ri][ci] += av[ri] * bv[ci];
        }
#pragma unroll
        for (int ri = 0; ri < 4; ++ri)
#pragma unroll
            for (int ci = 0; ci < 4; ++ci) {
                int i = tc + 64 * ci;
                abuf[(tr + 4 * ri) * 257 + i] = fmaxf(acc[ri][ci] + fc1b[i], 0.f);
            }
    }
    __syncthreads();
#pragma unroll
    for (int i = 0; i < 64; ++i) {
        int f = t + 256 * i, row = f >> 8, col = f & 255;
        wbuf[row * 257 + col] = fc2w[f];
    }
    __syncthreads();
    {  // GEMM2: 16 x 64 = a @ fc2^T, + h + fc2_b
        int tg = t >> 4, tc4 = t & 15;
        float acc2[4] = {0.f, 0.f, 0.f, 0.f};
#pragma unroll 8
        for (int k = 0; k < 256; ++k) {
            float a = abuf[tg * 257 + k];
#pragma unroll
            for (int ci = 0; ci < 4; ++ci) acc2[ci] += a * wbuf[(tc4 + 16 * ci) * 257 + k];
        }
#pragma unroll
        for (int ci = 0; ci < 4; ++ci) {
            int c = tc4 + 16 * ci;
            int row = r0 + tg;
            out[row * 64 + c] = h[row * 64 + c] + acc2[ci] + fc2b[c];
        }
    }
}

extern "C" void kernel_launch(void* const* d_in, const int* in_sizes, int n_in,
                              void* d_out, int out_size, void* d_ws, size_t ws_size,
                              hipStream_t stream) {
    const float* x    = (const float*)d_in[0];
    const float* stg  = (const float*)d_in[1];
    const int*   topk = (const int*)d_in[2];
    const float* qw   = (const float*)d_in[3];
    const float* qb   = (const float*)d_in[4];
    const float* kw   = (const float*)d_in[5];
    const float* kb   = (const float*)d_in[6];
    const float* lng  = (const float*)d_in[7];
    const float* lnb  = (const float*)d_in[8];
    const float* flng = (const float*)d_in[9];
    const float* flnb = (const float*)d_in[10];
    const float* fc1w = (const float*)d_in[11];
    const float* fc1b = (const float*)d_in[12];
    const float* fc2w = (const float*)d_in[13];
    const float* fc2b = (const float*)d_in[14];
    float* out = (float*)d_out;

    float* ws    = (float*)d_ws;
    float* xn    = ws;                          // 3,772,416
    float* qt    = xn + ROWSX * 64;             // 314,368
    float* cq    = qt + ROWSH * 64;             // 4,912
    float* M     = cq + ROWSH;                  // 4,096
    float* b2    = M + 4096;                    // 64
    float* vv    = b2 + 64;                     // 64
    float* cc    = vv + 64;                     // 64 (pad)
    float* sag   = cc + 64;                     // 18,095,808
    float* opart = sag + (size_t)ROWSH * TN;    // 2,514,944
    float* h     = opart + (size_t)KC * ROWSH * 64;  // 314,368  (~96 MiB total)

    fold_k<<<64, 64, 0, stream>>>(qw, qb, kw, kb, M, b2, vv, cc);
    ln_k<<<(ROWSX + 3) / 4, 256, 0, stream>>>(x, lng, lnb, xn, ROWSX);
    qt_k<<<(ROWSH + 3) / 4, 256, 0, stream>>>(xn, M, b2, vv, cc, qt, cq);
    score_k<<<dim3((TN + 127) / 128, (NN + 63) / 64, BB), 256, 0, stream>>>(qt, cq, xn, stg, sag);
    topk_k<<<ROWSH, 256, 0, stream>>>(sag, topk);
    ogemm_k<<<dim3(KC, (NN + 63) / 64, BB), 256, 0, stream>>>(sag, xn, opart);
    hred_k<<<(ROWSH * 64 + 255) / 256, 256, 0, stream>>>(opart, xn, h);
    ffn_k<<<ROWSH / 16, 256, 0, stream>>>(h, flng, flnb, fc1w, fc1b, fc2w, fc2b, out);
}

// Round 2
// 326.615 us; speedup vs baseline: 1.5385x; 1.5385x over previous
//
#include <hip/hip_runtime.h>

typedef __bf16 bf16x8 __attribute__((ext_vector_type(8)));
typedef float  f32x4  __attribute__((ext_vector_type(4)));

// Problem constants
constexpr int BB    = 16;
constexpr int TT    = 12;
constexpr int NN    = 307;
constexpr int TN    = TT * NN;        // 3684
constexpr int ROWSX = BB * TT * NN;   // 58944
constexpr int ROWSH = BB * NN;        // 4912
constexpr int SSTR  = 3840;           // padded K stride (= KC2*KCH2, mult of 32)
constexpr int KC2   = 6;              // o-GEMM K-split
constexpr int KCH2  = 640;            // 20 mfma k-steps per chunk
constexpr float SCALE = 0.125f;

__device__ __forceinline__ float wred_sum(float v) {
#pragma unroll
    for (int m = 32; m > 0; m >>= 1) v += __shfl_xor(v, m, 64);
    return v;
}

// ---------------------------------------------------------------------------
// Fold q/k projections: dg = q.k = qt.x_ + c  (see round-1 derivation)
// ---------------------------------------------------------------------------
__global__ void fold_k(const float* __restrict__ qw, const float* __restrict__ qb,
                       const float* __restrict__ kw, const float* __restrict__ kb,
                       float* __restrict__ M, float* __restrict__ b2,
                       float* __restrict__ vv, float* __restrict__ cc) {
    int e = blockIdx.x, d = threadIdx.x;
    float acc = 0.f;
    for (int dp = 0; dp < 64; ++dp) acc += qw[dp * 64 + e] * kw[dp * 64 + d];
    M[e * 64 + d] = acc;
    float vp = wred_sum(qw[d * 64 + e] * kb[d]);
    if (d == 0) vv[e] = vp;
    if (e == 0) {
        float b = 0.f;
        for (int dp = 0; dp < 64; ++dp) b += qb[dp] * kw[dp * 64 + d];
        b2[d] = b;
        float cp = wred_sum(qb[d] * kb[d]);
        if (d == 0) *cc = cp;
    }
}

// ---------------------------------------------------------------------------
// LayerNorm -> xnb (bf16, all rows) + y32 (fp32, t==11 slab only)
// ---------------------------------------------------------------------------
__global__ __launch_bounds__(256) void ln_k(const float* __restrict__ x,
                                            const float* __restrict__ g,
                                            const float* __restrict__ b,
                                            __bf16* __restrict__ xnb,
                                            float* __restrict__ y32) {
    int w = threadIdx.x >> 6, l = threadIdx.x & 63;
    int r = blockIdx.x * 4 + w;
    if (r >= ROWSX) return;
    float val = x[r * 64 + l];
    float mu  = wred_sum(val) * (1.f / 64.f);
    float dv  = val - mu;
    float var = wred_sum(dv * dv) * (1.f / 64.f);
    float xv  = dv * rsqrtf(var + 1e-5f) * g[l] + b[l];
    xnb[(size_t)r * 64 + l] = (__bf16)xv;
    int t = (r / NN) % TT;
    if (t == TT - 1) {
        int bbv = r / (NN * TT), n = r % NN;
        y32[(bbv * NN + n) * 64 + l] = xv;
    }
}

// ---------------------------------------------------------------------------
// Transpose xnb[b, j, d] -> xnT[b, d, j] (padded stride SSTR) for o-GEMM B
// ---------------------------------------------------------------------------
__global__ __launch_bounds__(256) void t_k(const __bf16* __restrict__ xnb,
                                           __bf16* __restrict__ xnT) {
    __shared__ unsigned short tile[64][65];
    int bb = blockIdx.y, j0 = blockIdx.x * 64, t = threadIdx.x;
    const unsigned short* src = (const unsigned short*)xnb;
    unsigned short* dst = (unsigned short*)xnT;
#pragma unroll
    for (int i = 0; i < 16; ++i) {
        int f = t + 256 * i, jr = f >> 6, dc = f & 63;
        int j = j0 + jr;
        tile[jr][dc] = (j < TN) ? src[((size_t)bb * TN + j) * 64 + dc] : (unsigned short)0;
    }
    __syncthreads();
#pragma unroll
    for (int i = 0; i < 16; ++i) {
        int f = t + 256 * i, d = f >> 6, jj = f & 63;
        dst[((size_t)bb * 64 + d) * SSTR + j0 + jj] = tile[jj][d];
    }
}

// ---------------------------------------------------------------------------
// qt[row] = y_ @ M + b2 (bf16 out);  cq[row] = y_.v + cc
// ---------------------------------------------------------------------------
__global__ __launch_bounds__(256) void qt_k(const float* __restrict__ y32,
                                            const float* __restrict__ M,
                                            const float* __restrict__ b2,
                                            const float* __restrict__ vv,
                                            const float* __restrict__ ccp,
                                            __bf16* __restrict__ qtb,
                                            float* __restrict__ cq) {
    int w = threadIdx.x >> 6, l = threadIdx.x & 63;
    int rr = blockIdx.x * 4 + w;
    if (rr >= ROWSH) return;
    float y = y32[rr * 64 + l];
    float acc = b2[l];
#pragma unroll
    for (int e = 0; e < 64; ++e) acc += __shfl(y, e, 64) * M[e * 64 + l];
    qtb[(size_t)rr * 64 + l] = (__bf16)acc;
    float cp = wred_sum(y * vv[l]);
    if (l == 0) cq[rr] = cp + *ccp;
}

// ---------------------------------------------------------------------------
// Score GEMM via MFMA 16x16x32 bf16; epilogue sigmoid*stg*scale -> sag (bf16)
// Per block: 64n x 128j, K=64. Wave w: rows n0+w*16..+15, all 128 j.
// Fragments loaded straight from global (L2-resident), no LDS.
// ---------------------------------------------------------------------------
__global__ __launch_bounds__(256) void score_k(const __bf16* __restrict__ qtb,
                                               const float* __restrict__ cq,
                                               const __bf16* __restrict__ xnb,
                                               const float* __restrict__ stg,
                                               __bf16* __restrict__ sag) {
    int bb = blockIdx.z, n0 = blockIdx.y * 64, j0 = blockIdx.x * 128;
    int w = threadIdx.x >> 6, lane = threadIdx.x & 63;
    int m16 = lane & 15, q4 = lane >> 4;
    const bf16x8* ap = (const bf16x8*)(qtb + ((size_t)bb * NN + n0 + w * 16 + m16) * 64);
    bf16x8 a0 = ap[q4], a1 = ap[q4 + 4];
    f32x4 acc[8];
#pragma unroll
    for (int jt = 0; jt < 8; ++jt) {
        const bf16x8* bp = (const bf16x8*)(xnb + ((size_t)bb * TN + j0 + jt * 16 + m16) * 64);
        bf16x8 b0 = bp[q4], b1 = bp[q4 + 4];
        f32x4 c = {0.f, 0.f, 0.f, 0.f};
        c = __builtin_amdgcn_mfma_f32_16x16x32_bf16(a0, b0, c, 0, 0, 0);
        c = __builtin_amdgcn_mfma_f32_16x16x32_bf16(a1, b1, c, 0, 0, 0);
        acc[jt] = c;
    }
    int nbase = n0 + w * 16 + q4 * 4;
#pragma unroll
    for (int r = 0; r < 4; ++r) {
        int n = nbase + r;
        if (n >= NN) continue;
        float cn = cq[bb * NN + n];
        size_t rb = ((size_t)bb * NN + n) * TN;
#pragma unroll
        for (int jt = 0; jt < 8; ++jt) {
            int j = j0 + jt * 16 + m16;
            if (j >= TN) continue;
            float dg = (acc[jt][r] + cn) * SCALE;
            float s  = 1.f / (1.f + __expf(-dg));
            sag[rb + j] = (__bf16)(s * stg[rb + j] * SCALE);
        }
    }
}

// ---------------------------------------------------------------------------
// Top-k + softmax, wave-per-row. Exact radix select on bf16 bits (2 passes),
// per-wave private 256-bin histogram, shuffle suffix-scan. Writes bf16
// weights to sagb (row stride SSTR, zero-padded tail for o-GEMM K-split).
// ---------------------------------------------------------------------------
__global__ __launch_bounds__(256) void topk_k(const __bf16* __restrict__ sagB,
                                              __bf16* __restrict__ sagb,
                                              const int* __restrict__ topk_p) {
    __shared__ int hist[4][256];
    const unsigned short* sag = (const unsigned short*)sagB;
    int wid = threadIdx.x >> 6, lane = threadIdx.x & 63;
    int row = blockIdx.x * 4 + wid;
    size_t base = (size_t)row * TN;
    unsigned short vals[58];
#pragma unroll
    for (int i = 0; i < 58; ++i) {
        int j = lane + 64 * i;
        vals[i] = (j < TN) ? sag[base + j] : (unsigned short)0;
    }
    // row max (all values >= 0 -> bf16 bits are order-preserving)
    int vmb = 0;
#pragma unroll
    for (int i = 0; i < 58; ++i) vmb = max(vmb, (int)vals[i]);
#pragma unroll
    for (int m = 32; m > 0; m >>= 1) vmb = max(vmb, __shfl_xor(vmb, m, 64));
    float vmax = __uint_as_float(((unsigned)vmb) << 16);

    int topkv = *topk_p;
    bool selAll = (topkv <= 0);
    unsigned thrb = 0;
    if (!selAll) {
        int kk = (topkv < 5) ? topkv * NN : topkv;
        if (kk > TN) kk = TN;
        int rk = kk;
        unsigned pref = 0;
#pragma unroll
        for (int pass = 0; pass < 2; ++pass) {
            int sh = 8 - 8 * pass;
            // zero own histogram
            int4 z; z.x = z.y = z.z = z.w = 0;
            ((int4*)&hist[wid][0])[lane] = z;
            __syncthreads();
#pragma unroll
            for (int i = 0; i < 58; ++i) {
                int j = lane + 64 * i;
                if (j < TN) {
                    unsigned u = vals[i];
                    bool m = (pass == 0) || ((u >> 8) == (pref >> 8));
                    if (m) atomicAdd(&hist[wid][(u >> sh) & 255], 1);
                }
            }
            __syncthreads();
            int4 hc = ((int4*)&hist[wid][0])[lane];
            int s3 = hc.w, s2 = hc.z + s3, s1 = hc.y + s2, s0 = hc.x + s1;
            int tot = s0, v = tot;
#pragma unroll
            for (int m = 1; m < 64; m <<= 1) {
                int t2 = __shfl_down(v, m, 64);
                if (lane + m < 64) v += t2;
            }
            int U = v - tot;  // suffix of strictly-higher lanes
            int S[4]  = {U + s0, U + s1, U + s2, U + s3};
            int SN[4] = {U + s1, U + s2, U + s3, U};
            int fbin = -1, frk = 0;
#pragma unroll
            for (int i = 0; i < 4; ++i)
                if (S[i] >= rk && SN[i] < rk) { fbin = 4 * lane + i; frk = rk - SN[i]; }
            unsigned long long bal = __ballot(fbin >= 0);
            int src = __ffsll((unsigned long long)bal) - 1;
            fbin = __shfl(fbin, src, 64);
            frk  = __shfl(frk, src, 64);
            pref |= ((unsigned)fbin) << sh;
            rk = frk;
            __syncthreads();
        }
        thrb = pref;  // bits of the kk-th largest bf16 value
    }

    // softmax over strictly-greater-than-threshold
    float local = 0.f;
#pragma unroll
    for (int i = 0; i < 58; ++i) {
        int j = lane + 64 * i;
        if (j < TN && (selAll || (unsigned)vals[i] > thrb))
            local += __expf(__uint_as_float(((unsigned)vals[i]) << 16) - vmax);
    }
    local = wred_sum(local);
    size_t ob = (size_t)row * SSTR;
    if (local > 0.f) {
        float inv = 1.f / local;
#pragma unroll
        for (int i = 0; i < 58; ++i) {
            int j = lane + 64 * i;
            if (j < TN) {
                unsigned u = vals[i];
                float wv = (selAll || u > thrb)
                               ? __expf(__uint_as_float(u << 16) - vmax) * inv : 0.f;
                sagb[ob + j] = (__bf16)wv;
            }
        }
    } else {  // degenerate: reference softmax of all-NEG_INF -> uniform
        float u = 1.f / (float)TN;
#pragma unroll
        for (int i = 0; i < 58; ++i) {
            int j = lane + 64 * i;
            if (j < TN) sagb[ob + j] = (__bf16)u;
        }
    }
    // zero the K-pad so o-GEMM can read full b128 fragments unguarded
    for (int p = lane; p < SSTR - TN; p += 64) sagb[ob + TN + p] = (__bf16)0.f;
}

// ---------------------------------------------------------------------------
// o-GEMM via MFMA, K-split: opart[kc][b,n,d] = sum_{j in chunk} w[n,j]*xn[j,d]
// Per block: 64n x 64d, K-chunk 640. Wave w: rows n0+w*16..+15.
// ---------------------------------------------------------------------------
__global__ __launch_bounds__(256) void ogemm_k(const __bf16* __restrict__ sagb,
                                               const __bf16* __restrict__ xnT,
                                               float* __restrict__ opart) {
    int bb = blockIdx.z, n0 = blockIdx.y * 64, kc = blockIdx.x;
    int w = threadIdx.x >> 6, lane = threadIdx.x & 63;
    int m16 = lane & 15, q4 = lane >> 4;
    const bf16x8* ap = (const bf16x8*)(sagb + ((size_t)bb * NN + n0 + w * 16 + m16) * SSTR);
    const bf16x8* bp0 = (const bf16x8*)(xnT + ((size_t)bb * 64 +  0 + m16) * SSTR);
    const bf16x8* bp1 = (const bf16x8*)(xnT + ((size_t)bb * 64 + 16 + m16) * SSTR);
    const bf16x8* bp2 = (const bf16x8*)(xnT + ((size_t)bb * 64 + 32 + m16) * SSTR);
    const bf16x8* bp3 = (const bf16x8*)(xnT + ((size_t)bb * 64 + 48 + m16) * SSTR);
    f32x4 acc[4];
#pragma unroll
    for (int i = 0; i < 4; ++i) acc[i] = (f32x4){0.f, 0.f, 0.f, 0.f};
    int cbase = (kc * KCH2) / 8 + q4;
#pragma unroll 4
    for (int ks = 0; ks < KCH2 / 32; ++ks) {
        int ci = cbase + ks * 4;
        bf16x8 a = ap[ci];
        acc[0] = __builtin_amdgcn_mfma_f32_16x16x32_bf16(a, bp0[ci], acc[0], 0, 0, 0);
        acc[1] = __builtin_amdgcn_mfma_f32_16x16x32_bf16(a, bp1[ci], acc[1], 0, 0, 0);
        acc[2] = __builtin_amdgcn_mfma_f32_16x16x32_bf16(a, bp2[ci], acc[2], 0, 0, 0);
        acc[3] = __builtin_amdgcn_mfma_f32_16x16x32_bf16(a, bp3[ci], acc[3], 0, 0, 0);
    }
    int nb = n0 + w * 16 + q4 * 4;
#pragma unroll
    for (int dt = 0; dt < 4; ++dt)
#pragma unroll
        for (int r = 0; r < 4; ++r) {
            int n = nb + r;
            if (n < NN)
                opart[((size_t)kc * ROWSH + bb * NN + n) * 64 + dt * 16 + m16] = acc[dt][r];
        }
}

// ---------------------------------------------------------------------------
// h = sum_kc opart + y_
// ---------------------------------------------------------------------------
__global__ void hred_k(const float* __restrict__ opart, const float* __restrict__ y32,
                       float* __restrict__ h) {
    int idx = blockIdx.x * 256 + threadIdx.x;
    if (idx >= ROWSH * 64) return;
    float acc = 0.f;
#pragma unroll
    for (int kc = 0; kc < KC2; ++kc) acc += opart[(size_t)kc * ROWSH * 64 + idx];
    h[idx] = acc + y32[idx];
}

// ---------------------------------------------------------------------------
// FFN: out = h + (relu(LN(h)@fc1^T + b1)@fc2^T + b2)    16 rows/block
// ---------------------------------------------------------------------------
__global__ __launch_bounds__(256) void ffn_k(const float* __restrict__ h,
                                             const float* __restrict__ g,
                                             const float* __restrict__ bln,
                                             const float* __restrict__ fc1w,
                                             const float* __restrict__ fc1b,
                                             const float* __restrict__ fc2w,
                                             const float* __restrict__ fc2b,
                                             float* __restrict__ out) {
    __shared__ float zbuf[16 * 65];
    __shared__ float wbuf[256 * 65];
    __shared__ float abuf[16 * 257];
    int t = threadIdx.x;
    int r0 = blockIdx.x * 16;
    int w = t >> 6, l = t & 63;
    for (int q = 0; q < 4; ++q) {
        int rloc = w * 4 + q;
        float val = h[(r0 + rloc) * 64 + l];
        float mu  = wred_sum(val) * (1.f / 64.f);
        float dv  = val - mu;
        float var = wred_sum(dv * dv) * (1.f / 64.f);
        zbuf[rloc * 65 + l] = dv * rsqrtf(var + 1e-5f) * g[l] + bln[l];
    }
#pragma unroll
    for (int i = 0; i < 64; ++i) {
        int f = t + 256 * i, row = f >> 6, col = f & 63;
        wbuf[row * 65 + col] = fc1w[f];
    }
    __syncthreads();
    {
        int tr = t >> 6, tc = t & 63;
        float acc[4][4];
#pragma unroll
        for (int a = 0; a < 4; ++a)
#pragma unroll
            for (int c = 0; c < 4; ++c) acc[a][c] = 0.f;
#pragma unroll 4
        for (int d = 0; d < 64; ++d) {
            float av[4], bv[4];
#pragma unroll
            for (int ri = 0; ri < 4; ++ri) av[ri] = zbuf[(tr + 4 * ri) * 65 + d];
#pragma unroll
            for (int ci = 0; ci < 4; ++ci) bv[ci] = wbuf[(tc + 64 * ci) * 65 + d];
#pragma unroll
            for (int ri = 0; ri < 4; ++ri)
#pragma unroll
                for (int ci = 0; ci < 4; ++ci) acc[ri][ci] += av[ri] * bv[ci];
        }
#pragma unroll
        for (int ri = 0; ri < 4; ++ri)
#pragma unroll
            for (int ci = 0; ci < 4; ++ci) {
                int i = tc + 64 * ci;
                abuf[(tr + 4 * ri) * 257 + i] = fmaxf(acc[ri][ci] + fc1b[i], 0.f);
            }
    }
    __syncthreads();
#pragma unroll
    for (int i = 0; i < 64; ++i) {
        int f = t + 256 * i, row = f >> 8, col = f & 255;
        wbuf[row * 257 + col] = fc2w[f];
    }
    __syncthreads();
    {
        int tg = t >> 4, tc4 = t & 15;
        float acc2[4] = {0.f, 0.f, 0.f, 0.f};
#pragma unroll 8
        for (int k = 0; k < 256; ++k) {
            float a = abuf[tg * 257 + k];
#pragma unroll
            for (int ci = 0; ci < 4; ++ci) acc2[ci] += a * wbuf[(tc4 + 16 * ci) * 257 + k];
        }
#pragma unroll
        for (int ci = 0; ci < 4; ++ci) {
            int c = tc4 + 16 * ci;
            int row = r0 + tg;
            out[row * 64 + c] = h[row * 64 + c] + acc2[ci] + fc2b[c];
        }
    }
}

extern "C" void kernel_launch(void* const* d_in, const int* in_sizes, int n_in,
                              void* d_out, int out_size, void* d_ws, size_t ws_size,
                              hipStream_t stream) {
    const float* x    = (const float*)d_in[0];
    const float* stg  = (const float*)d_in[1];
    const int*   topk = (const int*)d_in[2];
    const float* qw   = (const float*)d_in[3];
    const float* qb   = (const float*)d_in[4];
    const float* kw   = (const float*)d_in[5];
    const float* kb   = (const float*)d_in[6];
    const float* lng  = (const float*)d_in[7];
    const float* lnb  = (const float*)d_in[8];
    const float* flng = (const float*)d_in[9];
    const float* flnb = (const float*)d_in[10];
    const float* fc1w = (const float*)d_in[11];
    const float* fc1b = (const float*)d_in[12];
    const float* fc2w = (const float*)d_in[13];
    const float* fc2b = (const float*)d_in[14];
    float* out = (float*)d_out;

    // Workspace layout (floats). Totals 92.6 MB (round-1 layout proved >=96.5 MB available).
    float* ws = (float*)d_ws;
    __bf16* xnb = (__bf16*)ws;                              // (ROWSX+32)*64 ush = 1,887,232 f
    float* p1   = ws + 1887232;
    __bf16* xnT = (__bf16*)p1;                              // 16*64*3840 ush = 1,966,080 f
    float* p2   = p1 + 1966080;
    __bf16* qtb = (__bf16*)p2;                              // 4928*64 ush = 157,696 f
    float* y32  = p2 + 157696;                              // 314,368 f
    float* cq   = y32 + 314368;                             // 4,976 f
    float* M    = cq + 4976;                                // 4,096
    float* b2   = M + 4096;                                 // 64
    float* vv   = b2 + 64;                                  // 64
    float* cc   = vv + 64;                                  // 16
    __bf16* sag = (__bf16*)(cc + 16);                       // ROWSH*TN ush = 9,047,904 f
    __bf16* sagb = (__bf16*)((float*)sag + 9047904);        // 4928*3840 ush = 9,461,760 f
    float* h    = (float*)sagb + 9461760;                   // 314,368 f
    float* opart = (float*)xnb;  // alias: xnb dead after score_k; 6*ROWSH*64 = 1,886,208 f fits

    fold_k<<<64, 64, 0, stream>>>(qw, qb, kw, kb, M, b2, vv, cc);
    ln_k<<<(ROWSX + 3) / 4, 256, 0, stream>>>(x, lng, lnb, xnb, y32);
    t_k<<<dim3((TN + 63) / 64, BB), 256, 0, stream>>>(xnb, xnT);
    qt_k<<<(ROWSH + 3) / 4, 256, 0, stream>>>(y32, M, b2, vv, cc, qtb, cq);
    score_k<<<dim3((TN + 127) / 128, (NN + 63) / 64, BB), 256, 0, stream>>>(qtb, cq, xnb, stg, sag);
    topk_k<<<ROWSH / 4, 256, 0, stream>>>(sag, sagb, topk);
    ogemm_k<<<dim3(KC2, (NN + 63) / 64, BB), 256, 0, stream>>>(sagb, xnT, opart);
    hred_k<<<(ROWSH * 64 + 255) / 256, 256, 0, stream>>>(opart, y32, h);
    ffn_k<<<ROWSH / 16, 256, 0, stream>>>(h, flng, flnb, fc1w, fc1b, fc2w, fc2b, out);
}